// Round 15
// baseline (48.376 us; speedup 1.0000x reference)
//
#include <hip/hip_runtime.h>
#include <math.h>

#define NPV 3072
#define LDP 3073
#define EPSF 1e-8f
#define NMOM 52          // [0..6] w-moments, [7..51] 45-entry sym tensor
#define NSEG 64          // col-scan row segments (48 rows each)
#define SEGROWS 48
#define NCHUNK 12        // col chunks of 256 columns
#define NCOLBLK (NSEG * NCHUNK)   // 768 col-scan blocks
#define NROWBLK 768               // row-scan blocks (4 rows each)
#define NMRG 192                  // merge/moment blocks (16 cols each)

// Branchless insert of v into sorted-descending value triple.
#define INS3(v, a, b, c) do { \
    float _m1 = fminf((a), (v)); (a) = fmaxf((a), (v)); \
    float _m2 = fminf((b), _m1); (b) = fmaxf((b), _m1); \
    (c) = fmaxf((c), _m2); } while (0)

#define MRG3(x, y, z, a, b, c) do { \
    INS3((x), a, b, c); INS3((y), a, b, c); INS3((z), a, b, c); } while (0)

// Branchless insert of (v,i) into descending (a,ia)>=(b,ib)>=(c,ic).
#define INSJ(v, i, a, ia, b, ib, c, ic) do { \
    bool _g1 = (v) > (a); \
    bool _g2 = (v) > (b); \
    bool _g3 = (v) > (c); \
    float _nc = _g2 ? (b) : (_g3 ? (v) : (c)); \
    int  _nic = _g2 ? (ib) : (_g3 ? (i) : (ic)); \
    float _nb = _g1 ? (a) : (_g2 ? (v) : (b)); \
    int  _nib = _g1 ? (ia) : (_g2 ? (i) : (ib)); \
    (a) = _g1 ? (v) : (a); \
    (ia) = _g1 ? (i) : (ia); \
    (b) = _nb; (ib) = _nib; \
    (c) = _nc; (ic) = _nic; } while (0)

__device__ __forceinline__ void kinv6(const float* __restrict__ Kmat,
        float& ki0, float& ki1, float& ki2, float& ki3, float& ki4, float& ki5)
{
    float k00 = Kmat[0], k01 = Kmat[1], k02 = Kmat[2];
    float k10 = Kmat[3], k11 = Kmat[4], k12 = Kmat[5];
    float k20 = Kmat[6], k21 = Kmat[7], k22 = Kmat[8];
    float det = k00 * (k11 * k22 - k12 * k21) - k01 * (k10 * k22 - k12 * k20) + k02 * (k10 * k21 - k11 * k20);
    float id = 1.0f / det;
    ki0 = (k11 * k22 - k12 * k21) * id; ki1 = (k02 * k21 - k01 * k22) * id; ki2 = (k01 * k12 - k02 * k11) * id;
    ki3 = (k12 * k20 - k10 * k22) * id; ki4 = (k00 * k22 - k02 * k20) * id; ki5 = (k02 * k10 - k00 * k12) * id;
}

// ======== Kernel 1 (1536 blocks): col-scan (index-tracked, blocks <768) and
// row-scan (values-only tr, blocks >=768) run CONCURRENTLY — no dependency. ==
__global__ __launch_bounds__(256) void k_scan(const float* __restrict__ P,
        float* __restrict__ tr, float4* __restrict__ partv, int4* __restrict__ parti,
        int* __restrict__ ticket)
{
    int t = threadIdx.x;
    if (blockIdx.x == 0 && t == 0) *ticket = 0;

    if (blockIdx.x < NCOLBLK) {
        // ---- column scan: per-segment top-3 (value, row-index) per column ----
        int g = blockIdx.x;
        int j = (g % NCHUNK) * 256 + t;
        int i0 = (g / NCHUNK) * SEGROWS;
        const float* base = P + (size_t)i0 * LDP + j;
        float A0 = -1e30f, B0 = -1e30f, C0 = -1e30f; int IA0 = 0, IB0 = 0, IC0 = 0;
        float A1 = -1e30f, B1 = -1e30f, C1 = -1e30f; int IA1 = 0, IB1 = 0, IC1 = 0;
        float A2 = -1e30f, B2 = -1e30f, C2 = -1e30f; int IA2 = 0, IB2 = 0, IC2 = 0;
        float A3 = -1e30f, B3 = -1e30f, C3 = -1e30f; int IA3 = 0, IB3 = 0, IC3 = 0;
        float A4 = -1e30f, B4 = -1e30f, C4 = -1e30f; int IA4 = 0, IB4 = 0, IC4 = 0;
        float A5 = -1e30f, B5 = -1e30f, C5 = -1e30f; int IA5 = 0, IB5 = 0, IC5 = 0;
        float A6 = -1e30f, B6 = -1e30f, C6 = -1e30f; int IA6 = 0, IB6 = 0, IC6 = 0;
        float A7 = -1e30f, B7 = -1e30f, C7 = -1e30f; int IA7 = 0, IB7 = 0, IC7 = 0;
        #pragma unroll
        for (int r = 0; r < SEGROWS; r += 8) {
            float v0 = base[(size_t)(r + 0) * LDP];
            float v1 = base[(size_t)(r + 1) * LDP];
            float v2 = base[(size_t)(r + 2) * LDP];
            float v3 = base[(size_t)(r + 3) * LDP];
            float v4 = base[(size_t)(r + 4) * LDP];
            float v5 = base[(size_t)(r + 5) * LDP];
            float v6 = base[(size_t)(r + 6) * LDP];
            float v7 = base[(size_t)(r + 7) * LDP];
            int ib = i0 + r;
            INSJ(v0, ib + 0, A0, IA0, B0, IB0, C0, IC0);
            INSJ(v1, ib + 1, A1, IA1, B1, IB1, C1, IC1);
            INSJ(v2, ib + 2, A2, IA2, B2, IB2, C2, IC2);
            INSJ(v3, ib + 3, A3, IA3, B3, IB3, C3, IC3);
            INSJ(v4, ib + 4, A4, IA4, B4, IB4, C4, IC4);
            INSJ(v5, ib + 5, A5, IA5, B5, IB5, C5, IC5);
            INSJ(v6, ib + 6, A6, IA6, B6, IB6, C6, IC6);
            INSJ(v7, ib + 7, A7, IA7, B7, IB7, C7, IC7);
        }
#define MRGJ(x, ix, y, iy, z, iz) do { \
        INSJ(x, ix, A0, IA0, B0, IB0, C0, IC0); \
        INSJ(y, iy, A0, IA0, B0, IB0, C0, IC0); \
        INSJ(z, iz, A0, IA0, B0, IB0, C0, IC0); } while (0)
        MRGJ(A1, IA1, B1, IB1, C1, IC1);
        MRGJ(A2, IA2, B2, IB2, C2, IC2);
        MRGJ(A3, IA3, B3, IB3, C3, IC3);
        MRGJ(A4, IA4, B4, IB4, C4, IC4);
        MRGJ(A5, IA5, B5, IB5, C5, IC5);
        MRGJ(A6, IA6, B6, IB6, C6, IC6);
        MRGJ(A7, IA7, B7, IB7, C7, IC7);
#undef MRGJ
        size_t o = (size_t)(g / NCHUNK) * NPV + j;
        partv[o] = make_float4(A0, B0, C0, 0.f);
        parti[o] = make_int4(IA0, IB0, IC0, 0);
    } else {
        // ---- row scan: one wave per row, values-only top-3 -> tr[i] ----
        int g = blockIdx.x - NCOLBLK;
        int lane = t & 63;
        int i = g * 4 + (t >> 6);
        const float* row = P + (size_t)i * LDP;
        float a0 = -1e30f, b0 = -1e30f, c0 = -1e30f;
        float a1 = -1e30f, b1 = -1e30f, c1 = -1e30f;
        float a2 = -1e30f, b2 = -1e30f, c2 = -1e30f;
        float a3 = -1e30f, b3 = -1e30f, c3 = -1e30f;
        #pragma unroll
        for (int r = 0; r < 48; r += 4) {
            float v0 = row[(r + 0) * 64 + lane];
            float v1 = row[(r + 1) * 64 + lane];
            float v2 = row[(r + 2) * 64 + lane];
            float v3 = row[(r + 3) * 64 + lane];
            INS3(v0, a0, b0, c0);
            INS3(v1, a1, b1, c1);
            INS3(v2, a2, b2, c2);
            INS3(v3, a3, b3, c3);
        }
        MRG3(a1, b1, c1, a0, b0, c0);
        MRG3(a2, b2, c2, a0, b0, c0);
        MRG3(a3, b3, c3, a0, b0, c0);
        #pragma unroll
        for (int off = 1; off < 64; off <<= 1) {
            float xa = __shfl_xor(a0, off);
            float xb = __shfl_xor(b0, off);
            float xc = __shfl_xor(c0, off);
            MRG3(xa, xb, xc, a0, b0, c0);
        }
        if (lane == 0) tr[i] = c0;
    }
}

// ---------------- moments + tail helpers ------------------------------------
__device__ __forceinline__ void acc_pair(float* m, float w, float xs1, float ys1,
                                         float xs2, float ys2)
{
    m[0] += w;
    m[1] += w * xs1; m[2] += w * ys1; m[3] += w * (xs1 * xs1 + ys1 * ys1);
    m[4] += w * xs2; m[5] += w * ys2; m[6] += w * (xs2 * xs2 + ys2 * ys2);
    float a[9] = { xs1 * xs2, xs1 * ys2, xs1, ys1 * xs2, ys1 * ys2, ys1, xs2, ys2, 1.f };
    int idx = 7;
    #pragma unroll
    for (int u = 0; u < 9; ++u) {
        float wa = w * a[u];
        #pragma unroll
        for (int v = u; v < 9; ++v) { m[idx] = fmaf(wa, a[v], m[idx]); ++idx; }
    }
}

__device__ __forceinline__ void mm3r(const float* A, const float* B, float* C) {
    #pragma unroll
    for (int r = 0; r < 3; ++r)
        #pragma unroll
        for (int c = 0; c < 3; ++c)
            C[r * 3 + c] = A[r * 3 + 0] * B[0 + c] + A[r * 3 + 1] * B[3 + c] + A[r * 3 + 2] * B[6 + c];
}

__device__ __forceinline__ float det3(const float* M) {
    return M[0] * (M[4] * M[8] - M[5] * M[7])
         - M[1] * (M[3] * M[8] - M[5] * M[6])
         + M[2] * (M[3] * M[7] - M[4] * M[6]);
}

__device__ void ph_tail(const float* __restrict__ Kmat,
        const float* __restrict__ momp, float* __restrict__ out, int t)
{
    __shared__ float sMom[NMOM];
    __shared__ float sM[81], sY[81], sP[81], sT[81];
    __shared__ float sT1[9], sT2[9];

    if (t < NMOM) {
        float s = 0.f;
        #pragma unroll 8
        for (int b = 0; b < NMRG; ++b) s += momp[(size_t)b * 64 + t];
        sMom[t] = s;
    }
    __syncthreads();

    float ki0, ki1, ki2, ki3, ki4, ki5;
    kinv6(Kmat, ki0, ki1, ki2, ki3, ki4, ki5);
    float u0x = ki0 * 31.5f + ki1 * 23.5f + ki2;
    float u0y = ki3 * 31.5f + ki4 * 23.5f + ki5;

    float Sw = sMom[0];
    float ws = Sw + EPSF;
    float c1x = sMom[1] / ws, c1y = sMom[2] / ws;
    float c2x = sMom[4] / ws, c2y = sMom[5] / ws;
    float q1 = (sMom[3] - 2.f * (c1x * sMom[1] + c1y * sMom[2]) + (c1x * c1x + c1y * c1y) * Sw) / ws;
    float q2 = (sMom[6] - 2.f * (c2x * sMom[4] + c2y * sMom[5]) + (c2x * c2x + c2y * c2y) * Sw) / ws;
    float md1 = sqrtf(fmaxf(q1, 0.f) + EPSF);
    float md2 = sqrtf(fmaxf(q2, 0.f) + EPSF);
    float s1 = 1.4142135623730951f / (md1 + EPSF);
    float s2 = 1.4142135623730951f / (md2 + EPSF);

    if (t < 81) {
        int r = t / 9, c = t % 9;
        int u = r < c ? r : c, v = r < c ? c : r;
        int idx = 7 + u * 9 - (u * (u + 1)) / 2 + v;
        sM[t] = sMom[idx];
    }
    if (t == 0) {
        sT1[0] = s1; sT1[1] = 0.f; sT1[2] = -s1 * c1x;
        sT1[3] = 0.f; sT1[4] = s1; sT1[5] = -s1 * c1y;
        sT1[6] = 0.f; sT1[7] = 0.f; sT1[8] = 1.f;
        sT2[0] = s2; sT2[1] = 0.f; sT2[2] = -s2 * c2x;
        sT2[3] = 0.f; sT2[4] = s2; sT2[5] = -s2 * c2y;
        sT2[6] = 0.f; sT2[7] = 0.f; sT2[8] = 1.f;
    }
    __syncthreads();

    if (t < 81) {
        int k = t / 9, c = t % 9;
        float s = 0.f;
        #pragma unroll
        for (int l = 0; l < 9; ++l)
            s = fmaf(sM[k * 9 + l], sT1[(c / 3) * 3 + (l / 3)] * sT2[(c % 3) * 3 + (l % 3)], s);
        sY[t] = s;
    }
    __syncthreads();
    if (t < 81) {
        int r = t / 9, c = t % 9;
        float s = 0.f;
        #pragma unroll
        for (int k = 0; k < 9; ++k)
            s = fmaf(sT1[(r / 3) * 3 + (k / 3)] * sT2[(r % 3) * 3 + (k % 3)], sY[k * 9 + c], s);
        sP[t] = s;
    }
    __syncthreads();
    if (t < 81) {
        int r = t / 9, c = t % 9;
        float lam = sP[0] + sP[10] + sP[20] + sP[30] + sP[40] + sP[50] + sP[60] + sP[70] + sP[80];
        float il = 1.f / (lam + 1e-30f);
        sM[t] = ((r == c ? lam : 0.f) - sP[t]) * il;
    }
    __syncthreads();

#define MM81(DST, A, B) \
    if (t < 81) { \
        int _r = t / 9, _c = t % 9; \
        float _s = 0.f; \
        _Pragma("unroll") \
        for (int _k = 0; _k < 9; ++_k) _s = fmaf(A[_r * 9 + _k], B[_k * 9 + _c], _s); \
        DST[t] = _s; \
    } \
    __syncthreads();

    MM81(sY, sM, sM)   // P2   (kept)
    MM81(sP, sY, sY)   // P4
    MM81(sT, sP, sP)   // P8
    MM81(sP, sT, sT)   // P16  (kept)
    MM81(sT, sP, sP)   // P32
    MM81(sM, sT, sP)   // R  = P32*P16
    MM81(sT, sM, sY)   // P50 = R*P2
#undef MM81

    if (t < 64) {
        float v9[9];
        float nrm = 0.f;
        #pragma unroll
        for (int r = 0; r < 9; ++r) {
            float s = 0.f;
            #pragma unroll
            for (int c = 0; c < 9; ++c) s += sT[r * 9 + c];
            v9[r] = s * (1.f / 3.f);
            nrm += v9[r] * v9[r];
        }
        nrm = sqrtf(nrm) + EPSF;
        #pragma unroll
        for (int r = 0; r < 9; ++r) v9[r] /= nrm;

        float C1x = c1x + u0x, C1y = c1y + u0y;
        float C2x = c2x + u0x, C2y = c2y + u0y;
        float T1f[9] = { s1, 0.f, -s1 * C1x, 0.f, s1, -s1 * C1y, 0.f, 0.f, 1.f };
        float T2t[9] = { s2, 0.f, 0.f, 0.f, s2, 0.f, -s2 * C2x, -s2 * C2y, 1.f };
        float M1[9], Ee[9];
        mm3r(v9, T1f, M1);
        mm3r(T2t, M1, Ee);

        float B[9];
        #pragma unroll
        for (int r = 0; r < 3; ++r)
            #pragma unroll
            for (int c = 0; c < 3; ++c)
                B[r * 3 + c] = Ee[r] * Ee[c] + Ee[3 + r] * Ee[3 + c] + Ee[6 + r] * Ee[6 + c];
        float lam3 = B[0] + B[4] + B[8];
        float il3 = 1.f / (lam3 + 1e-30f);

        int parity = t & 1;
        float P1[9];
        #pragma unroll
        for (int k = 0; k < 9; ++k) {
            float d = (k == 0 || k == 4 || k == 8) ? lam3 : 0.f;
            P1[k] = (parity ? (d - B[k]) : B[k]) * il3;
        }
        float P2[9], P4[9], P8[9], P16[9], P32[9], R1[9], P50[9];
        mm3r(P1, P1, P2);
        mm3r(P2, P2, P4);
        mm3r(P4, P4, P8);
        mm3r(P8, P8, P16);
        mm3r(P16, P16, P32);
        mm3r(P32, P16, R1);
        mm3r(R1, P2, P50);
        float vx = (P50[0] + P50[1] + P50[2]) * 0.57735026918962584f;
        float vy = (P50[3] + P50[4] + P50[5]) * 0.57735026918962584f;
        float vz = (P50[6] + P50[7] + P50[8]) * 0.57735026918962584f;
        float vn = sqrtf(vx * vx + vy * vy + vz * vz) + EPSF;
        vx /= vn; vy /= vn; vz /= vn;

        float v3x = __shfl(vx, 1), v3y = __shfl(vy, 1), v3z = __shfl(vz, 1);

        if (t == 0) {
            float v1[3] = { vx, vy, vz };
            float v3[3] = { v3x, v3y, v3z };
            float v2[3];
            v2[0] = v3[1] * v1[2] - v3[2] * v1[1];
            v2[1] = v3[2] * v1[0] - v3[0] * v1[2];
            v2[2] = v3[0] * v1[1] - v3[1] * v1[0];
            float n2 = sqrtf(v2[0] * v2[0] + v2[1] * v2[1] + v2[2] * v2[2]) + EPSF;
            v2[0] /= n2; v2[1] /= n2; v2[2] /= n2;
            float V[9];
            #pragma unroll
            for (int r = 0; r < 3; ++r) { V[r * 3 + 0] = v1[r]; V[r * 3 + 1] = v2[r]; V[r * 3 + 2] = v3[r]; }
            float dV = det3(V);
            float sV = (dV > 0.f) ? 1.f : ((dV < 0.f) ? -1.f : 0.f);
            V[2] *= sV; V[5] *= sV; V[8] *= sV;
            float Ev1[3], Ev2[3];
            #pragma unroll
            for (int r = 0; r < 3; ++r) {
                Ev1[r] = Ee[r * 3] * V[0] + Ee[r * 3 + 1] * V[3] + Ee[r * 3 + 2] * V[6];
                Ev2[r] = Ee[r * 3] * V[1] + Ee[r * 3 + 1] * V[4] + Ee[r * 3 + 2] * V[7];
            }
            float s1n = sqrtf(Ev1[0] * Ev1[0] + Ev1[1] * Ev1[1] + Ev1[2] * Ev1[2]);
            float s2n = sqrtf(Ev2[0] * Ev2[0] + Ev2[1] * Ev2[1] + Ev2[2] * Ev2[2]);
            float s_avg = (s1n + s2n) * 0.5f;
            float u1[3], u2[3];
            #pragma unroll
            for (int r = 0; r < 3; ++r) { u1[r] = Ev1[r] / (s1n + EPSF); u2[r] = Ev2[r] / (s2n + EPSF); }
            #pragma unroll
            for (int r = 0; r < 3; ++r)
                #pragma unroll
                for (int c = 0; c < 3; ++c)
                    out[r * 3 + c] = s_avg * (u1[r] * V[c * 3 + 0] + u2[r] * V[c * 3 + 1]);
        }
    }
}

// ======== Kernel 2 (192 blocks): merge col partials (with indices) -> global
// col top-3 -> filter by tr/0.01 -> 52 moments -> last-ticket tail. ==========
__global__ __launch_bounds__(256) void k_merge_mom_tail(const float* __restrict__ Kmat,
        const float* __restrict__ tr, const float4* __restrict__ partv,
        const int4* __restrict__ parti, float* __restrict__ momp,
        int* __restrict__ ticket, float* __restrict__ out)
{
    __shared__ float sRed[4][NMOM];
    __shared__ int slast;
    int t = threadIdx.x;
    int sub = t & 15;
    int j = blockIdx.x * 16 + (t >> 4);

    // Merge 64 per-segment triples: 16 threads/col x 4 segments each.
    float A = -1e30f, B = -1e30f, C = -1e30f;
    int IA = 0, IB = 0, IC = 0;
    #pragma unroll
    for (int k = 0; k < 4; ++k) {
        size_t o = (size_t)(sub + (k << 4)) * NPV + j;
        float4 v = partv[o];
        int4  iv = parti[o];
        INSJ(v.x, iv.x, A, IA, B, IB, C, IC);
        INSJ(v.y, iv.y, A, IA, B, IB, C, IC);
        INSJ(v.z, iv.z, A, IA, B, IB, C, IC);
    }
    #pragma unroll
    for (int off = 1; off < 16; off <<= 1) {
        float xa = __shfl_xor(A, off), xb = __shfl_xor(B, off), xc = __shfl_xor(C, off);
        int   ya = __shfl_xor(IA, off), yb = __shfl_xor(IB, off), yc = __shfl_xor(IC, off);
        INSJ(xa, ya, A, IA, B, IB, C, IC);
        INSJ(xb, yb, A, IA, B, IB, C, IC);
        INSJ(xc, yc, A, IA, B, IB, C, IC);
    }

    // sub==0 owns column j's top-3 (v, rowidx): filter + accumulate moments.
    float m[NMOM];
    #pragma unroll
    for (int k = 0; k < NMOM; ++k) m[k] = 0.f;
    if (sub == 0) {
        float ki0, ki1, ki2, ki3, ki4, ki5;
        kinv6(Kmat, ki0, ki1, ki2, ki3, ki4, ki5);
        float xj = (float)(j & 63) - 31.5f, yj = (float)(j >> 6) - 23.5f;
        float xs2 = ki0 * xj + ki1 * yj;
        float ys2 = ki3 * xj + ki4 * yj;
#define ACCI(V, I) do { \
        if ((V) > 0.01f && (V) >= tr[I]) { \
            float _xg = (float)((I) & 63) - 31.5f, _yg = (float)((I) >> 6) - 23.5f; \
            float xs1 = ki0 * _xg + ki1 * _yg; \
            float ys1 = ki3 * _xg + ki4 * _yg; \
            acc_pair(m, (V), xs1, ys1, xs2, ys2); \
        } } while (0)
        ACCI(A, IA);
        ACCI(B, IB);
        ACCI(C, IC);
#undef ACCI
    }
    // Owners sit at lanes {0,16,32,48} of each wave: xor-16 then xor-32 reduce.
    #pragma unroll
    for (int k = 0; k < NMOM; ++k) {
        m[k] += __shfl_xor(m[k], 16);
        m[k] += __shfl_xor(m[k], 32);
    }
    int lane = t & 63, wid = t >> 6;
    if (lane == 0) {
        #pragma unroll
        for (int k = 0; k < NMOM; ++k) sRed[wid][k] = m[k];
    }
    __syncthreads();
    if (t < NMOM)
        momp[(size_t)blockIdx.x * 64 + t] = sRed[0][t] + sRed[1][t] + sRed[2][t] + sRed[3][t];

    __threadfence();
    __syncthreads();
    if (t == 0) slast = (atomicAdd(ticket, 1) == NMRG - 1) ? 1 : 0;
    __syncthreads();
    if (!slast) return;
    __threadfence();
    ph_tail(Kmat, momp, out, t);
}

extern "C" void kernel_launch(void* const* d_in, const int* in_sizes, int n_in,
                              void* d_out, int out_size, void* d_ws, size_t ws_size,
                              hipStream_t stream)
{
    const float* P = (const float*)d_in[0];
    const float* K = (const float*)d_in[1];
    float* out = (float*)d_out;

    float* fws    = (float*)d_ws;
    float* tr     = fws;                           // 3072
    float* momp   = tr + NPV;                      // 192*64 = 12288
    int*   ticket = (int*)(momp + NMRG * 64);      // 16 ints pad
    float4* partv = (float4*)(ticket + 16);        // 64*3072 float4 (offset 61504 B, 16B-aligned)
    int4*   parti = (int4*)(partv + (size_t)NSEG * NPV); // 64*3072 int4

    k_scan<<<NCOLBLK + NROWBLK, 256, 0, stream>>>(P, tr, partv, parti, ticket);
    k_merge_mom_tail<<<NMRG, 256, 0, stream>>>(K, tr, partv, parti, momp, ticket, out);
}